// Round 26
// baseline (233.878 us; speedup 1.0000x reference)
//
#include <hip/hip_runtime.h>
#include <hip/hip_bf16.h>
#include <math.h>

#define N_NODES 50000
#define N_EDGES 800000
#define BN_EPS  1e-5f
#define SCAN_NB 49     // ceil(50000/1024)
#define AGG_NB  2048   // agg grid blocks

typedef float floatx2 __attribute__((ext_vector_type(2)));
typedef _Float16 half2_t __attribute__((ext_vector_type(2)));

#if defined(__has_builtin) && __has_builtin(__builtin_amdgcn_fdot2)
#define FDOT2(a, b, c) __builtin_amdgcn_fdot2((a), (b), (c), false)
#else
#define FDOT2(a, b, c) ((c) + (float)(a).x * (float)(b).x + (float)(a).y * (float)(b).y)
#endif

union h2u { half2_t h; unsigned u; };

// ---- workspace layout (float-element offsets) ----
#define OFS_RELW   0                    // 200*128 padded relw
#define OFS_KVP    25600                // 50000 rows x 64 uints: k half + v half (256B/row)
#define OFS_Q      3225600              // 50000*128 padded q
#define OFS_BNPART 9625600              // 200 * AGG_NB
#define OFS_BNSC   10035200
#define OFS_BNSH   10035328
#define OFS_CNT    10035456
#define OFS_PART   10085632
#define OFS_BSUM   10135808
#define OFS_OFFS   10135872
#define OFS_RANK   10186048             // 800000 ints
#define OFS_PEDGE  10986048             // 800000 uints: src | ety<<17
#define OFS_WT     11786048             // 4*50*104 packed half2 W
#define WS_ELEMS   11806848

// fused prep: zero cnt (blocks 0..195), relw (196..295), wth pack (296..377)
__global__ __launch_bounds__(256) void prep_kernel(
    const float* __restrict__ wcomp, const float* __restrict__ ratt,
    const float* __restrict__ Wk, const float* __restrict__ Wq,
    const float* __restrict__ Wv, const float* __restrict__ Ws,
    float* __restrict__ relw, unsigned* __restrict__ Wth,
    int* __restrict__ cnt)
{
    const int b = blockIdx.x;
    const int tid = threadIdx.x;
    if (b < 196) {
        int i = b * 256 + tid;
        if (i < 50176) cnt[i] = 0;
    } else if (b < 296) {
        int o = (b - 196) * 256 + tid;
        if (o < 200 * 128) {
            int r = o / 128, c = o % 128;
            float acc = 0.f;
            if (c < 100) {
                #pragma unroll 10
                for (int k = 0; k < 50; ++k)
                    acc += wcomp[r * 50 + k] * ratt[k * 100 + c];
            }
            relw[o] = acc;
        }
    } else {
        int o = (b - 296) * 256 + tid;
        if (o < 4 * 50 * 104) {
            int m = o / 5200, rem = o % 5200, d2 = rem / 104, c = rem % 104;
            const float* W = (m == 0) ? Wk : (m == 1) ? Wq : (m == 2) ? Wv : Ws;
            float a = (c < 100) ? W[c * 100 + 2 * d2]     : 0.f;
            float bb = (c < 100) ? W[c * 100 + 2 * d2 + 1] : 0.f;
            h2u cv; cv.h = half2_t{(_Float16)a, (_Float16)bb};
            Wth[o] = cv.u;
        }
    }
}

// fused projections: proven fdot2 config (512 thr, 4x4 tile, 64-node tile,
// half2 LDS, XOR swizzle). k,v -> fp8 into ONE interleaved kvp row
// (k words 0-31, v words 32-63; 256B aligned; pads 0); q -> fp32 128-col
// rows (pad 0); s -> fp32 100-col rows.
__global__ __launch_bounds__(512) void proj_kernel(
    const float* __restrict__ X, const unsigned* __restrict__ Wth,
    const float* __restrict__ bk, const float* __restrict__ bq,
    const float* __restrict__ bv, const float* __restrict__ bs,
    unsigned* __restrict__ kvp, float* __restrict__ qo,
    float* __restrict__ so)
{
    __shared__ unsigned Xth[50][68];    // 13.6 KB
    __shared__ unsigned Wlh[50][104];   // 20.8 KB
    const int tid = threadIdx.x;
    const int nb  = blockIdx.x * 64;
    const int m   = blockIdx.y;

    const float* bp = (m == 0) ? bk : (m == 1) ? bq : (m == 2) ? bv : bs;

    for (int idx = tid; idx < 1300; idx += 512) {
        int r = idx / 26, c4 = idx % 26;
        uint4 w = ((const uint4*)(Wth + m * 5200 + r * 104))[c4];
        *(uint4*)&Wlh[r][c4 * 4] = w;
    }
    for (int idx = tid; idx < 1600; idx += 512) {
        int n = idx / 25, d4 = idx % 25;
        int node = nb + n;
        float4 x = (node < N_NODES)
                   ? ((const float4*)(X + (size_t)node * 100))[d4]
                   : make_float4(0.f, 0.f, 0.f, 0.f);
        const int col = n ^ ((d4 & 7) << 2);
        h2u c0, c1;
        c0.h = half2_t{(_Float16)x.x, (_Float16)x.y};
        c1.h = half2_t{(_Float16)x.z, (_Float16)x.w};
        Xth[2 * d4][col]     = c0.u;
        Xth[2 * d4 + 1][col] = c1.u;
    }
    __syncthreads();

    const int nt  = tid & 15;        // node group: nodes 4nt..4nt+3
    const int ct  = tid >> 4;        // col group 0..31 (25 active compute)
    const bool act = (ct < 25);
    const int cts  = act ? ct : 24;

    float acc[4][4];
    #pragma unroll
    for (int i = 0; i < 4; ++i)
        #pragma unroll
        for (int j = 0; j < 4; ++j) acc[i][j] = 0.f;

    #pragma unroll 5
    for (int d2 = 0; d2 < 50; ++d2) {
        const int key = ((d2 >> 1) & 7) << 2;
        const uint4 xv = *(const uint4*)&Xth[d2][(4 * nt) ^ key];
        const uint4 wv = *(const uint4*)&Wlh[d2][4 * cts];
        h2u x0, x1, x2, x3, w0, w1, w2, w3;
        x0.u = xv.x; x1.u = xv.y; x2.u = xv.z; x3.u = xv.w;
        w0.u = wv.x; w1.u = wv.y; w2.u = wv.z; w3.u = wv.w;
        acc[0][0] = FDOT2(x0.h, w0.h, acc[0][0]);
        acc[0][1] = FDOT2(x0.h, w1.h, acc[0][1]);
        acc[0][2] = FDOT2(x0.h, w2.h, acc[0][2]);
        acc[0][3] = FDOT2(x0.h, w3.h, acc[0][3]);
        acc[1][0] = FDOT2(x1.h, w0.h, acc[1][0]);
        acc[1][1] = FDOT2(x1.h, w1.h, acc[1][1]);
        acc[1][2] = FDOT2(x1.h, w2.h, acc[1][2]);
        acc[1][3] = FDOT2(x1.h, w3.h, acc[1][3]);
        acc[2][0] = FDOT2(x2.h, w0.h, acc[2][0]);
        acc[2][1] = FDOT2(x2.h, w1.h, acc[2][1]);
        acc[2][2] = FDOT2(x2.h, w2.h, acc[2][2]);
        acc[2][3] = FDOT2(x2.h, w3.h, acc[2][3]);
        acc[3][0] = FDOT2(x3.h, w0.h, acc[3][0]);
        acc[3][1] = FDOT2(x3.h, w1.h, acc[3][1]);
        acc[3][2] = FDOT2(x3.h, w2.h, acc[3][2]);
        acc[3][3] = FDOT2(x3.h, w3.h, acc[3][3]);
    }

    const float4 bb = act ? *(const float4*)(bp + ct * 4)
                          : make_float4(0.f, 0.f, 0.f, 0.f);
    if (m == 0 || m == 2) {
        const int wofs = (m == 0) ? ct : (32 + ct);
        #pragma unroll
        for (int i = 0; i < 4; ++i) {
            const int node = nb + nt * 4 + i;
            if (node < N_NODES) {
                unsigned wdo = 0u;
                if (act) {
                    int wd = 0;
                    wd = __builtin_amdgcn_cvt_pk_fp8_f32(
                        acc[i][0] + bb.x, acc[i][1] + bb.y, wd, false);
                    wd = __builtin_amdgcn_cvt_pk_fp8_f32(
                        acc[i][2] + bb.z, acc[i][3] + bb.w, wd, true);
                    wdo = (unsigned)wd;
                }
                kvp[(size_t)node * 64 + wofs] = wdo;
            }
        }
    } else if (m == 1) {
        #pragma unroll
        for (int i = 0; i < 4; ++i) {
            const int node = nb + nt * 4 + i;
            if (node < N_NODES) {
                float4 r = act ? make_float4(acc[i][0] + bb.x, acc[i][1] + bb.y,
                                             acc[i][2] + bb.z, acc[i][3] + bb.w)
                               : make_float4(0.f, 0.f, 0.f, 0.f);
                *(float4*)(qo + (size_t)node * 128 + ct * 4) = r;
            }
        }
    } else {
        if (act) {
            #pragma unroll
            for (int i = 0; i < 4; ++i) {
                const int node = nb + nt * 4 + i;
                if (node < N_NODES) {
                    float4 r = make_float4(acc[i][0] + bb.x, acc[i][1] + bb.y,
                                           acc[i][2] + bb.z, acc[i][3] + bb.w);
                    *(float4*)(so + (size_t)node * 100 + ct * 4) = r;
                }
            }
        }
    }
}

// histogram + per-edge rank (atomicAdd return value)
__global__ __launch_bounds__(256) void hist_kernel(
    const int* __restrict__ dst, int* __restrict__ cnt, int* __restrict__ rank)
{
    int e = blockIdx.x * 256 + threadIdx.x;
    if (e < N_EDGES) rank[e] = atomicAdd(&cnt[dst[e]], 1);
}

__global__ __launch_bounds__(1024) void scanA_kernel(
    const int* __restrict__ cnt, int* __restrict__ partial, int* __restrict__ bsum)
{
    __shared__ int buf[1024];
    int tid = threadIdx.x;
    int i = blockIdx.x * 1024 + tid;
    int val = (i < N_NODES) ? cnt[i] : 0;
    buf[tid] = val;
    __syncthreads();
    for (int off = 1; off < 1024; off <<= 1) {
        int t = (tid >= off) ? buf[tid - off] : 0;
        __syncthreads();
        buf[tid] += t;
        __syncthreads();
    }
    int incl = buf[tid];
    if (i < N_NODES) partial[i] = incl - val;
    if (tid == 1023) bsum[blockIdx.x] = incl;
}

__global__ __launch_bounds__(1024) void scanB_kernel(
    const int* __restrict__ partial, const int* __restrict__ bsum,
    int* __restrict__ offs)
{
    __shared__ int bs[64];
    int tid = threadIdx.x;
    if (tid < SCAN_NB) bs[tid] = bsum[tid];
    __syncthreads();
    if (tid == 0) {
        int run = 0;
        for (int b = 0; b < SCAN_NB; ++b) { int t = bs[b]; bs[b] = run; run += t; }
    }
    __syncthreads();
    for (int i = tid; i < N_NODES; i += 1024) offs[i] = partial[i] + bs[i >> 10];
    if (tid == 0) offs[N_NODES] = N_EDGES;
}

// scatter: NO atomics -- pos = offs[dst] + rank. ONE 4B word per edge
// (src | ety<<17); per-node entries cluster into ~1 cache line.
__global__ __launch_bounds__(256) void scatter_kernel(
    const int* __restrict__ src, const int* __restrict__ dst,
    const int* __restrict__ ety, const int* __restrict__ offs,
    const int* __restrict__ rank, unsigned* __restrict__ pedge)
{
    int e = blockIdx.x * 256 + threadIdx.x;
    if (e >= N_EDGES) return;
    int d = dst[e];
    pedge[offs[d] + rank[e]] = (unsigned)src[e] | ((unsigned)ety[e] << 17);
}

// fused attention + aggregate: one wave per node. q row held in registers
// (constant per node); per edge: gather k+v from the SAME 256B kvp row,
// lane-parallel dot + 64-lane butterfly reduce, exp, accumulate.
// Then gated combine + BN partials. No attp array, no second edge pass.
__global__ __launch_bounds__(256) void agg_kernel(
    const int* __restrict__ offs, const unsigned* __restrict__ pedge,
    const unsigned* __restrict__ kvp, const float* __restrict__ q,
    const float* __restrict__ relw, const float* __restrict__ alpha,
    float* __restrict__ out, float* __restrict__ bnpart)
{
    __shared__ float ls[100], lq[100];
    const int tid = threadIdx.x;
    if (tid < 100) { ls[tid] = 0.f; lq[tid] = 0.f; }
    __syncthreads();
    const int lane = tid & 63;
    const int gwave = blockIdx.x * 4 + (tid >> 6);
    const int nwaves = AGG_NB * 4;
    const float a = 1.f / (1.f + __expf(-alpha[0]));
    const float b = 1.f - a;
    const int cl = lane;             // lane owns columns 2cl, 2cl+1 (cl<50 active out)
    const bool act = (cl < 50);
    const unsigned short* kv16 = (const unsigned short*)kvp;
    float sx = 0.f, sy = 0.f, qx = 0.f, qy = 0.f;

    for (int n = gwave; n < N_NODES; n += nwaves) {
        const int beg = offs[n], end = offs[n + 1];
        const float2 qv = ((const float2*)(q + (size_t)n * 128))[cl]; // pad 0
        float ax = 0.f, ay = 0.f, wsum = 0.f;
        int i = beg;
        for (; i + 2 <= end; i += 2) {
            const unsigned p0 = pedge[i], p1 = pedge[i + 1];
            const int s0 = (int)(p0 & 0x1FFFFu), t0 = (int)(p0 >> 17);
            const int s1 = (int)(p1 & 0x1FFFFu), t1 = (int)(p1 >> 17);
            const unsigned short* r0 = kv16 + (size_t)s0 * 128;
            const unsigned short* r1 = kv16 + (size_t)s1 * 128;
            const unsigned short kh0 = r0[cl],      kh1 = r1[cl];
            const unsigned short vh0 = r0[64 + cl], vh1 = r1[64 + cl];
            const float2 wv0 = ((const float2*)(relw + t0 * 128))[cl];
            const float2 wv1 = ((const float2*)(relw + t1 * 128))[cl];
            const floatx2 k0 = __builtin_amdgcn_cvt_pk_f32_fp8((int)kh0, false);
            const floatx2 k1 = __builtin_amdgcn_cvt_pk_f32_fp8((int)kh1, false);
            float pa = k0[0] * wv0.x * qv.x + k0[1] * wv0.y * qv.y;
            float pb = k1[0] * wv1.x * qv.x + k1[1] * wv1.y * qv.y;
            #pragma unroll
            for (int off = 32; off > 0; off >>= 1) {
                pa += __shfl_xor(pa, off, 64);
                pb += __shfl_xor(pb, off, 64);
            }
            const float w0 = __expf(pa), w1 = __expf(pb);
            wsum += w0 + w1;
            const floatx2 v0 = __builtin_amdgcn_cvt_pk_f32_fp8((int)vh0, false);
            const floatx2 v1 = __builtin_amdgcn_cvt_pk_f32_fp8((int)vh1, false);
            ax += w0 * v0[0] + w1 * v1[0];
            ay += w0 * v0[1] + w1 * v1[1];
        }
        for (; i < end; ++i) {
            const unsigned p0 = pedge[i];
            const int s0 = (int)(p0 & 0x1FFFFu), t0 = (int)(p0 >> 17);
            const unsigned short* r0 = kv16 + (size_t)s0 * 128;
            const unsigned short kh0 = r0[cl];
            const unsigned short vh0 = r0[64 + cl];
            const float2 wv0 = ((const float2*)(relw + t0 * 128))[cl];
            const floatx2 k0 = __builtin_amdgcn_cvt_pk_f32_fp8((int)kh0, false);
            float pa = k0[0] * wv0.x * qv.x + k0[1] * wv0.y * qv.y;
            #pragma unroll
            for (int off = 32; off > 0; off >>= 1)
                pa += __shfl_xor(pa, off, 64);
            const float w0 = __expf(pa);
            wsum += w0;
            const floatx2 v0 = __builtin_amdgcn_cvt_pk_f32_fp8((int)vh0, false);
            ax += w0 * v0[0];
            ay += w0 * v0[1];
        }
        const float inv = (wsum > 0.f) ? 1.f / wsum : 0.f;
        if (act) {
            float2* po = (float2*)(out + (size_t)n * 100);
            float2 cur = po[cl];
            float v0 = a * cur.x + b * ax * inv;
            float v1 = a * cur.y + b * ay * inv;
            po[cl] = make_float2(v0, v1);
            sx += v0; qx += v0 * v0;
            sy += v1; qy += v1 * v1;
        }
    }
    if (act) {
        atomicAdd(&ls[2 * cl], sx);     atomicAdd(&ls[2 * cl + 1], sy);
        atomicAdd(&lq[2 * cl], qx);     atomicAdd(&lq[2 * cl + 1], qy);
    }
    __syncthreads();
    if (tid < 100) {
        bnpart[(size_t)tid * AGG_NB + blockIdx.x]         = ls[tid];
        bnpart[(size_t)(tid + 100) * AGG_NB + blockIdx.x] = lq[tid];
    }
}

__global__ __launch_bounds__(256) void bnfin_kernel(
    const float* __restrict__ bnpart,
    const float* __restrict__ gamma, const float* __restrict__ beta,
    float* __restrict__ bnsc, float* __restrict__ bnsh)
{
    const int c = blockIdx.x * 4 + (threadIdx.x >> 6);
    const int lane = threadIdx.x & 63;
    if (c >= 100) return;
    float s = 0.f, q = 0.f;
    for (int b2 = lane; b2 < AGG_NB; b2 += 64) {
        s += bnpart[(size_t)c * AGG_NB + b2];
        q += bnpart[(size_t)(c + 100) * AGG_NB + b2];
    }
    #pragma unroll
    for (int off = 32; off > 0; off >>= 1) {
        s += __shfl_xor(s, off, 64);
        q += __shfl_xor(q, off, 64);
    }
    if (lane == 0) {
        const float inv_n = 1.f / (float)N_NODES;
        float mean = s * inv_n;
        float var = q * inv_n - mean * mean;
        float sc = gamma[c] * rsqrtf(var + BN_EPS);
        bnsc[c] = sc;
        bnsh[c] = beta[c] - mean * sc;
    }
}

// fused: BN-apply+tanh (blocks < 2048) and r_out GEMM (blocks >= 2048)
__global__ __launch_bounds__(256) void applyrout_kernel(
    float* __restrict__ out, const float* __restrict__ bnsc,
    const float* __restrict__ bnsh,
    const float* __restrict__ rf, const float* __restrict__ Wr,
    const float* __restrict__ br)
{
    if (blockIdx.x < 2048) {
        const int total4 = N_NODES * 25;
        for (int idx = blockIdx.x * 256 + threadIdx.x; idx < total4; idx += 2048 * 256) {
            float4* p = ((float4*)out) + idx;
            const int c = (idx % 25) * 4;
            float4 t = *p;
            t.x = tanhf(t.x * bnsc[c]     + bnsh[c]);
            t.y = tanhf(t.y * bnsc[c + 1] + bnsh[c + 1]);
            t.z = tanhf(t.z * bnsc[c + 2] + bnsh[c + 2]);
            t.w = tanhf(t.w * bnsc[c + 3] + bnsh[c + 3]);
            *p = t;
        }
    } else {
        int o = (blockIdx.x - 2048) * 256 + threadIdx.x;
        if (o < 200 * 100) {
            int r = o / 100, c = o % 100;
            float acc = br[c];
            #pragma unroll 10
            for (int d = 0; d < 100; ++d) acc += rf[r * 100 + d] * Wr[c * 100 + d];
            out[N_NODES * 100 + o] = acc;
        }
    }
}

extern "C" void kernel_launch(void* const* d_in, const int* in_sizes, int n_in,
                              void* d_out, int out_size, void* d_ws, size_t ws_size,
                              hipStream_t stream) {
    const float* X     = (const float*)d_in[0];
    const float* rfeat = (const float*)d_in[1];
    const int*   src   = (const int*)d_in[2];
    const int*   dst   = (const int*)d_in[3];
    const int*   ety   = (const int*)d_in[4];
    const float* Wsw   = (const float*)d_in[6];
    const float* Wsb   = (const float*)d_in[7];
    const float* Wkw   = (const float*)d_in[8];
    const float* Wkb   = (const float*)d_in[9];
    const float* Wqw   = (const float*)d_in[10];
    const float* Wqb   = (const float*)d_in[11];
    const float* Wvw   = (const float*)d_in[12];
    const float* Wvb   = (const float*)d_in[13];
    const float* Wrw   = (const float*)d_in[14];
    const float* Wrb   = (const float*)d_in[15];
    const float* ratt  = (const float*)d_in[16];
    const float* wcomp = (const float*)d_in[17];
    const float* alpha = (const float*)d_in[18];
    const float* gamma = (const float*)d_in[20];
    const float* beta  = (const float*)d_in[21];

    float* out = (float*)d_out;
    float* ws  = (float*)d_ws;
    if (ws_size < (size_t)WS_ELEMS * sizeof(float)) return;

    float* relw          = ws + OFS_RELW;
    unsigned* kvp        = (unsigned*)(ws + OFS_KVP);
    float* q             = ws + OFS_Q;
    float* bnpart        = ws + OFS_BNPART;
    float* bnsc          = ws + OFS_BNSC;
    float* bnsh          = ws + OFS_BNSH;
    unsigned* Wth        = (unsigned*)(ws + OFS_WT);
    int* cnt             = (int*)(ws + OFS_CNT);
    int* partial         = (int*)(ws + OFS_PART);
    int* bsum            = (int*)(ws + OFS_BSUM);
    int* offs            = (int*)(ws + OFS_OFFS);
    int* rank            = (int*)(ws + OFS_RANK);
    unsigned* pedge      = (unsigned*)(ws + OFS_PEDGE);

    prep_kernel<<<196 + 100 + 82, 256, 0, stream>>>(
        wcomp, ratt, Wkw, Wqw, Wvw, Wsw, relw, Wth, cnt);
    proj_kernel<<<dim3((N_NODES + 63) / 64, 4), 512, 0, stream>>>(
        X, Wth, Wkb, Wqb, Wvb, Wsb, kvp, q, out);

    hist_kernel<<<(N_EDGES + 255) / 256, 256, 0, stream>>>(dst, cnt, rank);
    scanA_kernel<<<SCAN_NB, 1024, 0, stream>>>(cnt, partial, bsum);
    scanB_kernel<<<1, 1024, 0, stream>>>(partial, bsum, offs);
    scatter_kernel<<<(N_EDGES + 255) / 256, 256, 0, stream>>>(
        src, dst, ety, offs, rank, pedge);

    agg_kernel<<<AGG_NB, 256, 0, stream>>>(
        offs, pedge, kvp, q, relw, alpha, out, bnpart);
    bnfin_kernel<<<25, 256, 0, stream>>>(bnpart, gamma, beta, bnsc, bnsh);
    applyrout_kernel<<<2048 + (20000 + 255) / 256, 256, 0, stream>>>(
        out, bnsc, bnsh, rfeat, Wrw, Wrb);
}

// Round 27
// 228.918 us; speedup vs baseline: 1.0217x; 1.0217x over previous
//
#include <hip/hip_runtime.h>
#include <hip/hip_bf16.h>
#include <math.h>

#define N_NODES 50000
#define N_EDGES 800000
#define BN_EPS  1e-5f
#define SCAN_NB 49     // ceil(50000/1024)
#define AGG_NB  2048   // agg grid blocks

typedef float floatx2 __attribute__((ext_vector_type(2)));
typedef _Float16 half2_t __attribute__((ext_vector_type(2)));

#if defined(__has_builtin) && __has_builtin(__builtin_amdgcn_fdot2)
#define FDOT2(a, b, c) __builtin_amdgcn_fdot2((a), (b), (c), false)
#else
#define FDOT2(a, b, c) ((c) + (float)(a).x * (float)(b).x + (float)(a).y * (float)(b).y)
#endif

union h2u { half2_t h; unsigned u; };

// ---- workspace layout (float-element offsets) ----
#define OFS_RELW   0                    // 200*128 padded relw
#define OFS_KVP    25600                // 50000 rows x 64 uints: k half + v half (256B/row)
#define OFS_Q      3225600              // 50000*128 padded q
#define OFS_BNPART 9625600              // 200 * AGG_NB
#define OFS_BNSC   10035200
#define OFS_BNSH   10035328
#define OFS_CNT    10035456
#define OFS_PART   10085632
#define OFS_BSUM   10135808
#define OFS_OFFS   10135872
#define OFS_RANK   10186048             // 800000 ints
#define OFS_PEDGE  10986048             // 800000 uints: src | ety<<17
#define OFS_WT     11786048             // 4*50*104 packed half2 W
#define WS_ELEMS   11806848

// fused prep: zero cnt (blocks 0..195), relw (196..295), wth pack (296..377)
__global__ __launch_bounds__(256) void prep_kernel(
    const float* __restrict__ wcomp, const float* __restrict__ ratt,
    const float* __restrict__ Wk, const float* __restrict__ Wq,
    const float* __restrict__ Wv, const float* __restrict__ Ws,
    float* __restrict__ relw, unsigned* __restrict__ Wth,
    int* __restrict__ cnt)
{
    const int b = blockIdx.x;
    const int tid = threadIdx.x;
    if (b < 196) {
        int i = b * 256 + tid;
        if (i < 50176) cnt[i] = 0;
    } else if (b < 296) {
        int o = (b - 196) * 256 + tid;
        if (o < 200 * 128) {
            int r = o / 128, c = o % 128;
            float acc = 0.f;
            if (c < 100) {
                #pragma unroll 10
                for (int k = 0; k < 50; ++k)
                    acc += wcomp[r * 50 + k] * ratt[k * 100 + c];
            }
            relw[o] = acc;
        }
    } else {
        int o = (b - 296) * 256 + tid;
        if (o < 4 * 50 * 104) {
            int m = o / 5200, rem = o % 5200, d2 = rem / 104, c = rem % 104;
            const float* W = (m == 0) ? Wk : (m == 1) ? Wq : (m == 2) ? Wv : Ws;
            float a = (c < 100) ? W[c * 100 + 2 * d2]     : 0.f;
            float bb = (c < 100) ? W[c * 100 + 2 * d2 + 1] : 0.f;
            h2u cv; cv.h = half2_t{(_Float16)a, (_Float16)bb};
            Wth[o] = cv.u;
        }
    }
}

// fused projections: proven fdot2 config (512 thr, 4x4 tile, 64-node tile,
// half2 LDS, XOR swizzle). k,v -> fp8 into ONE interleaved kvp row
// (k words 0-31, v words 32-63; 256B aligned; pads 0); q -> fp32 128-col
// rows (pad 0); s -> fp32 100-col rows.
__global__ __launch_bounds__(512) void proj_kernel(
    const float* __restrict__ X, const unsigned* __restrict__ Wth,
    const float* __restrict__ bk, const float* __restrict__ bq,
    const float* __restrict__ bv, const float* __restrict__ bs,
    unsigned* __restrict__ kvp, float* __restrict__ qo,
    float* __restrict__ so)
{
    __shared__ unsigned Xth[50][68];    // 13.6 KB
    __shared__ unsigned Wlh[50][104];   // 20.8 KB
    const int tid = threadIdx.x;
    const int nb  = blockIdx.x * 64;
    const int m   = blockIdx.y;

    const float* bp = (m == 0) ? bk : (m == 1) ? bq : (m == 2) ? bv : bs;

    for (int idx = tid; idx < 1300; idx += 512) {
        int r = idx / 26, c4 = idx % 26;
        uint4 w = ((const uint4*)(Wth + m * 5200 + r * 104))[c4];
        *(uint4*)&Wlh[r][c4 * 4] = w;
    }
    for (int idx = tid; idx < 1600; idx += 512) {
        int n = idx / 25, d4 = idx % 25;
        int node = nb + n;
        float4 x = (node < N_NODES)
                   ? ((const float4*)(X + (size_t)node * 100))[d4]
                   : make_float4(0.f, 0.f, 0.f, 0.f);
        const int col = n ^ ((d4 & 7) << 2);
        h2u c0, c1;
        c0.h = half2_t{(_Float16)x.x, (_Float16)x.y};
        c1.h = half2_t{(_Float16)x.z, (_Float16)x.w};
        Xth[2 * d4][col]     = c0.u;
        Xth[2 * d4 + 1][col] = c1.u;
    }
    __syncthreads();

    const int nt  = tid & 15;        // node group: nodes 4nt..4nt+3
    const int ct  = tid >> 4;        // col group 0..31 (25 active compute)
    const bool act = (ct < 25);
    const int cts  = act ? ct : 24;

    float acc[4][4];
    #pragma unroll
    for (int i = 0; i < 4; ++i)
        #pragma unroll
        for (int j = 0; j < 4; ++j) acc[i][j] = 0.f;

    #pragma unroll 5
    for (int d2 = 0; d2 < 50; ++d2) {
        const int key = ((d2 >> 1) & 7) << 2;
        const uint4 xv = *(const uint4*)&Xth[d2][(4 * nt) ^ key];
        const uint4 wv = *(const uint4*)&Wlh[d2][4 * cts];
        h2u x0, x1, x2, x3, w0, w1, w2, w3;
        x0.u = xv.x; x1.u = xv.y; x2.u = xv.z; x3.u = xv.w;
        w0.u = wv.x; w1.u = wv.y; w2.u = wv.z; w3.u = wv.w;
        acc[0][0] = FDOT2(x0.h, w0.h, acc[0][0]);
        acc[0][1] = FDOT2(x0.h, w1.h, acc[0][1]);
        acc[0][2] = FDOT2(x0.h, w2.h, acc[0][2]);
        acc[0][3] = FDOT2(x0.h, w3.h, acc[0][3]);
        acc[1][0] = FDOT2(x1.h, w0.h, acc[1][0]);
        acc[1][1] = FDOT2(x1.h, w1.h, acc[1][1]);
        acc[1][2] = FDOT2(x1.h, w2.h, acc[1][2]);
        acc[1][3] = FDOT2(x1.h, w3.h, acc[1][3]);
        acc[2][0] = FDOT2(x2.h, w0.h, acc[2][0]);
        acc[2][1] = FDOT2(x2.h, w1.h, acc[2][1]);
        acc[2][2] = FDOT2(x2.h, w2.h, acc[2][2]);
        acc[2][3] = FDOT2(x2.h, w3.h, acc[2][3]);
        acc[3][0] = FDOT2(x3.h, w0.h, acc[3][0]);
        acc[3][1] = FDOT2(x3.h, w1.h, acc[3][1]);
        acc[3][2] = FDOT2(x3.h, w2.h, acc[3][2]);
        acc[3][3] = FDOT2(x3.h, w3.h, acc[3][3]);
    }

    const float4 bb = act ? *(const float4*)(bp + ct * 4)
                          : make_float4(0.f, 0.f, 0.f, 0.f);
    if (m == 0 || m == 2) {
        const int wofs = (m == 0) ? ct : (32 + ct);
        #pragma unroll
        for (int i = 0; i < 4; ++i) {
            const int node = nb + nt * 4 + i;
            if (node < N_NODES) {
                unsigned wdo = 0u;
                if (act) {
                    int wd = 0;
                    wd = __builtin_amdgcn_cvt_pk_fp8_f32(
                        acc[i][0] + bb.x, acc[i][1] + bb.y, wd, false);
                    wd = __builtin_amdgcn_cvt_pk_fp8_f32(
                        acc[i][2] + bb.z, acc[i][3] + bb.w, wd, true);
                    wdo = (unsigned)wd;
                }
                kvp[(size_t)node * 64 + wofs] = wdo;
            }
        }
    } else if (m == 1) {
        #pragma unroll
        for (int i = 0; i < 4; ++i) {
            const int node = nb + nt * 4 + i;
            if (node < N_NODES) {
                float4 r = act ? make_float4(acc[i][0] + bb.x, acc[i][1] + bb.y,
                                             acc[i][2] + bb.z, acc[i][3] + bb.w)
                               : make_float4(0.f, 0.f, 0.f, 0.f);
                *(float4*)(qo + (size_t)node * 128 + ct * 4) = r;
            }
        }
    } else {
        if (act) {
            #pragma unroll
            for (int i = 0; i < 4; ++i) {
                const int node = nb + nt * 4 + i;
                if (node < N_NODES) {
                    float4 r = make_float4(acc[i][0] + bb.x, acc[i][1] + bb.y,
                                           acc[i][2] + bb.z, acc[i][3] + bb.w);
                    *(float4*)(so + (size_t)node * 100 + ct * 4) = r;
                }
            }
        }
    }
}

// histogram + per-edge rank (atomicAdd return value)
__global__ __launch_bounds__(256) void hist_kernel(
    const int* __restrict__ dst, int* __restrict__ cnt, int* __restrict__ rank)
{
    int e = blockIdx.x * 256 + threadIdx.x;
    if (e < N_EDGES) rank[e] = atomicAdd(&cnt[dst[e]], 1);
}

__global__ __launch_bounds__(1024) void scanA_kernel(
    const int* __restrict__ cnt, int* __restrict__ partial, int* __restrict__ bsum)
{
    __shared__ int buf[1024];
    int tid = threadIdx.x;
    int i = blockIdx.x * 1024 + tid;
    int val = (i < N_NODES) ? cnt[i] : 0;
    buf[tid] = val;
    __syncthreads();
    for (int off = 1; off < 1024; off <<= 1) {
        int t = (tid >= off) ? buf[tid - off] : 0;
        __syncthreads();
        buf[tid] += t;
        __syncthreads();
    }
    int incl = buf[tid];
    if (i < N_NODES) partial[i] = incl - val;
    if (tid == 1023) bsum[blockIdx.x] = incl;
}

__global__ __launch_bounds__(1024) void scanB_kernel(
    const int* __restrict__ partial, const int* __restrict__ bsum,
    int* __restrict__ offs)
{
    __shared__ int bs[64];
    int tid = threadIdx.x;
    if (tid < SCAN_NB) bs[tid] = bsum[tid];
    __syncthreads();
    if (tid == 0) {
        int run = 0;
        for (int b = 0; b < SCAN_NB; ++b) { int t = bs[b]; bs[b] = run; run += t; }
    }
    __syncthreads();
    for (int i = tid; i < N_NODES; i += 1024) offs[i] = partial[i] + bs[i >> 10];
    if (tid == 0) offs[N_NODES] = N_EDGES;
}

// scatter: NO atomics -- pos = offs[dst] + rank. ONE 4B word per edge.
__global__ __launch_bounds__(256) void scatter_kernel(
    const int* __restrict__ src, const int* __restrict__ dst,
    const int* __restrict__ ety, const int* __restrict__ offs,
    const int* __restrict__ rank, unsigned* __restrict__ pedge)
{
    int e = blockIdx.x * 256 + threadIdx.x;
    if (e >= N_EDGES) return;
    int d = dst[e];
    pedge[offs[d] + rank[e]] = (unsigned)src[e] | ((unsigned)ety[e] << 17);
}

// fused attention + aggregate: one wave per node; 4 edges per iteration,
// one per 16-lane group. Lane j of group g dots quads {j, j+16} of edge
// (i+g) against the node's q (preloaded regs); 4-step group reduce; one
// exp per group; weights/srcs broadcast via shfl feed the 64-lane V
// accumulation (lane owns cols 2l,2l+1). Tail: clamp index, zero weight.
__global__ __launch_bounds__(256) void agg_kernel(
    const int* __restrict__ offs, const unsigned* __restrict__ pedge,
    const unsigned* __restrict__ kvp, const float* __restrict__ q,
    const float* __restrict__ relw, const float* __restrict__ alpha,
    float* __restrict__ out, float* __restrict__ bnpart)
{
    __shared__ float ls[100], lq[100];
    const int tid = threadIdx.x;
    if (tid < 100) { ls[tid] = 0.f; lq[tid] = 0.f; }
    __syncthreads();
    const int lane = tid & 63;
    const int j    = lane & 15;       // quad index within group
    const int g16  = lane >> 4;       // edge group 0..3
    const int gwave = blockIdx.x * 4 + (tid >> 6);
    const int nwaves = AGG_NB * 4;
    const float a = 1.f / (1.f + __expf(-alpha[0]));
    const float b = 1.f - a;
    const bool act = (lane < 50);
    const unsigned short* kv16 = (const unsigned short*)kvp;
    float sx = 0.f, sy = 0.f, qx = 0.f, qy = 0.f;

    for (int n = gwave; n < N_NODES; n += nwaves) {
        const int beg = offs[n], end = offs[n + 1];
        const float4 qa = ((const float4*)(q + (size_t)n * 128))[j];
        const float4 qb = ((const float4*)(q + (size_t)n * 128))[j + 16];
        float ax = 0.f, ay = 0.f, wsum = 0.f;
        for (int i = beg; i < end; i += 4) {
            const int ne = end - i;
            const int gg = (g16 < ne) ? g16 : (ne - 1);
            const unsigned pw = pedge[i + gg];
            const int s_ = (int)(pw & 0x1FFFFu);
            const int t_ = (int)(pw >> 17);
            const unsigned* kr = kvp + (size_t)s_ * 64;
            const unsigned kh0 = kr[j];
            const unsigned kh1 = kr[j + 16];
            const float4 w0 = ((const float4*)(relw + t_ * 128))[j];
            const float4 w1 = ((const float4*)(relw + t_ * 128))[j + 16];
            const floatx2 ka = __builtin_amdgcn_cvt_pk_f32_fp8((int)kh0, false);
            const floatx2 kb = __builtin_amdgcn_cvt_pk_f32_fp8((int)kh0, true);
            const floatx2 kc = __builtin_amdgcn_cvt_pk_f32_fp8((int)kh1, false);
            const floatx2 kd = __builtin_amdgcn_cvt_pk_f32_fp8((int)kh1, true);
            float pa = ka[0] * w0.x * qa.x + ka[1] * w0.y * qa.y
                     + kb[0] * w0.z * qa.z + kb[1] * w0.w * qa.w
                     + kc[0] * w1.x * qb.x + kc[1] * w1.y * qb.y
                     + kd[0] * w1.z * qb.z + kd[1] * w1.w * qb.w;
            #pragma unroll
            for (int off = 1; off < 16; off <<= 1)
                pa += __shfl_xor(pa, off, 16);
            const float wgt = (g16 < ne) ? __expf(pa) : 0.f;
            // broadcast weights and src ids across the wave
            const float wA = __shfl(wgt, 0, 64),  wB = __shfl(wgt, 16, 64);
            const float wC = __shfl(wgt, 32, 64), wD = __shfl(wgt, 48, 64);
            const int   sA = __shfl(s_, 0, 64),   sB = __shfl(s_, 16, 64);
            const int   sC = __shfl(s_, 32, 64),  sD = __shfl(s_, 48, 64);
            wsum += wA + wB + wC + wD;
            const unsigned short vA = kv16[(size_t)sA * 128 + 64 + lane];
            const unsigned short vB = kv16[(size_t)sB * 128 + 64 + lane];
            const unsigned short vC = kv16[(size_t)sC * 128 + 64 + lane];
            const unsigned short vD = kv16[(size_t)sD * 128 + 64 + lane];
            const floatx2 fA = __builtin_amdgcn_cvt_pk_f32_fp8((int)vA, false);
            const floatx2 fB = __builtin_amdgcn_cvt_pk_f32_fp8((int)vB, false);
            const floatx2 fC = __builtin_amdgcn_cvt_pk_f32_fp8((int)vC, false);
            const floatx2 fD = __builtin_amdgcn_cvt_pk_f32_fp8((int)vD, false);
            ax += wA * fA[0] + wB * fB[0] + wC * fC[0] + wD * fD[0];
            ay += wA * fA[1] + wB * fB[1] + wC * fC[1] + wD * fD[1];
        }
        const float inv = (wsum > 0.f) ? 1.f / wsum : 0.f;
        if (act) {
            float2* po = (float2*)(out + (size_t)n * 100);
            float2 cur = po[lane];
            float v0 = a * cur.x + b * ax * inv;
            float v1 = a * cur.y + b * ay * inv;
            po[lane] = make_float2(v0, v1);
            sx += v0; qx += v0 * v0;
            sy += v1; qy += v1 * v1;
        }
    }
    if (act) {
        atomicAdd(&ls[2 * lane], sx);     atomicAdd(&ls[2 * lane + 1], sy);
        atomicAdd(&lq[2 * lane], qx);     atomicAdd(&lq[2 * lane + 1], qy);
    }
    __syncthreads();
    if (tid < 100) {
        bnpart[(size_t)tid * AGG_NB + blockIdx.x]         = ls[tid];
        bnpart[(size_t)(tid + 100) * AGG_NB + blockIdx.x] = lq[tid];
    }
}

__global__ __launch_bounds__(256) void bnfin_kernel(
    const float* __restrict__ bnpart,
    const float* __restrict__ gamma, const float* __restrict__ beta,
    float* __restrict__ bnsc, float* __restrict__ bnsh)
{
    const int c = blockIdx.x * 4 + (threadIdx.x >> 6);
    const int lane = threadIdx.x & 63;
    if (c >= 100) return;
    float s = 0.f, q = 0.f;
    for (int b2 = lane; b2 < AGG_NB; b2 += 64) {
        s += bnpart[(size_t)c * AGG_NB + b2];
        q += bnpart[(size_t)(c + 100) * AGG_NB + b2];
    }
    #pragma unroll
    for (int off = 32; off > 0; off >>= 1) {
        s += __shfl_xor(s, off, 64);
        q += __shfl_xor(q, off, 64);
    }
    if (lane == 0) {
        const float inv_n = 1.f / (float)N_NODES;
        float mean = s * inv_n;
        float var = q * inv_n - mean * mean;
        float sc = gamma[c] * rsqrtf(var + BN_EPS);
        bnsc[c] = sc;
        bnsh[c] = beta[c] - mean * sc;
    }
}

// fused: BN-apply+tanh (blocks < 2048) and r_out GEMM (blocks >= 2048)
__global__ __launch_bounds__(256) void applyrout_kernel(
    float* __restrict__ out, const float* __restrict__ bnsc,
    const float* __restrict__ bnsh,
    const float* __restrict__ rf, const float* __restrict__ Wr,
    const float* __restrict__ br)
{
    if (blockIdx.x < 2048) {
        const int total4 = N_NODES * 25;
        for (int idx = blockIdx.x * 256 + threadIdx.x; idx < total4; idx += 2048 * 256) {
            float4* p = ((float4*)out) + idx;
            const int c = (idx % 25) * 4;
            float4 t = *p;
            t.x = tanhf(t.x * bnsc[c]     + bnsh[c]);
            t.y = tanhf(t.y * bnsc[c + 1] + bnsh[c + 1]);
            t.z = tanhf(t.z * bnsc[c + 2] + bnsh[c + 2]);
            t.w = tanhf(t.w * bnsc[c + 3] + bnsh[c + 3]);
            *p = t;
        }
    } else {
        int o = (blockIdx.x - 2048) * 256 + threadIdx.x;
        if (o < 200 * 100) {
            int r = o / 100, c = o % 100;
            float acc = br[c];
            #pragma unroll 10
            for (int d = 0; d < 100; ++d) acc += rf[r * 100 + d] * Wr[c * 100 + d];
            out[N_NODES * 100 + o] = acc;
        }
    }
}

extern "C" void kernel_launch(void* const* d_in, const int* in_sizes, int n_in,
                              void* d_out, int out_size, void* d_ws, size_t ws_size,
                              hipStream_t stream) {
    const float* X     = (const float*)d_in[0];
    const float* rfeat = (const float*)d_in[1];
    const int*   src   = (const int*)d_in[2];
    const int*   dst   = (const int*)d_in[3];
    const int*   ety   = (const int*)d_in[4];
    const float* Wsw   = (const float*)d_in[6];
    const float* Wsb   = (const float*)d_in[7];
    const float* Wkw   = (const float*)d_in[8];
    const float* Wkb   = (const float*)d_in[9];
    const float* Wqw   = (const float*)d_in[10];
    const float* Wqb   = (const float*)d_in[11];
    const float* Wvw   = (const float*)d_in[12];
    const float* Wvb   = (const float*)d_in[13];
    const float* Wrw   = (const float*)d_in[14];
    const float* Wrb   = (const float*)d_in[15];
    const float* ratt  = (const float*)d_in[16];
    const float* wcomp = (const float*)d_in[17];
    const float* alpha = (const float*)d_in[18];
    const float* gamma = (const float*)d_in[20];
    const float* beta  = (const float*)d_in[21];

    float* out = (float*)d_out;
    float* ws  = (float*)d_ws;
    if (ws_size < (size_t)WS_ELEMS * sizeof(float)) return;

    float* relw          = ws + OFS_RELW;
    unsigned* kvp        = (unsigned*)(ws + OFS_KVP);
    float* q             = ws + OFS_Q;
    float* bnpart        = ws + OFS_BNPART;
    float* bnsc          = ws + OFS_BNSC;
    float* bnsh          = ws + OFS_BNSH;
    unsigned* Wth        = (unsigned*)(ws + OFS_WT);
    int* cnt             = (int*)(ws + OFS_CNT);
    int* partial         = (int*)(ws + OFS_PART);
    int* bsum            = (int*)(ws + OFS_BSUM);
    int* offs            = (int*)(ws + OFS_OFFS);
    int* rank            = (int*)(ws + OFS_RANK);
    unsigned* pedge      = (unsigned*)(ws + OFS_PEDGE);

    prep_kernel<<<196 + 100 + 82, 256, 0, stream>>>(
        wcomp, ratt, Wkw, Wqw, Wvw, Wsw, relw, Wth, cnt);
    proj_kernel<<<dim3((N_NODES + 63) / 64, 4), 512, 0, stream>>>(
        X, Wth, Wkb, Wqb, Wvb, Wsb, kvp, q, out);

    hist_kernel<<<(N_EDGES + 255) / 256, 256, 0, stream>>>(dst, cnt, rank);
    scanA_kernel<<<SCAN_NB, 1024, 0, stream>>>(cnt, partial, bsum);
    scanB_kernel<<<1, 1024, 0, stream>>>(partial, bsum, offs);
    scatter_kernel<<<(N_EDGES + 255) / 256, 256, 0, stream>>>(
        src, dst, ety, offs, rank, pedge);

    agg_kernel<<<AGG_NB, 256, 0, stream>>>(
        offs, pedge, kvp, q, relw, alpha, out, bnpart);
    bnfin_kernel<<<25, 256, 0, stream>>>(bnpart, gamma, beta, bnsc, bnsh);
    applyrout_kernel<<<2048 + (20000 + 255) / 256, 256, 0, stream>>>(
        out, bnsc, bnsh, rfeat, Wrw, Wrb);
}

// Round 28
// 216.612 us; speedup vs baseline: 1.0797x; 1.0568x over previous
//
#include <hip/hip_runtime.h>
#include <hip/hip_bf16.h>
#include <math.h>

#define N_NODES 50000
#define N_EDGES 800000
#define BN_EPS  1e-5f
#define SCAN_NB 49     // ceil(50000/1024)
#define AGG_NB  2048   // agg grid blocks

typedef float floatx2 __attribute__((ext_vector_type(2)));
typedef _Float16 half2_t __attribute__((ext_vector_type(2)));

#if defined(__has_builtin) && __has_builtin(__builtin_amdgcn_fdot2)
#define FDOT2(a, b, c) __builtin_amdgcn_fdot2((a), (b), (c), false)
#else
#define FDOT2(a, b, c) ((c) + (float)(a).x * (float)(b).x + (float)(a).y * (float)(b).y)
#endif

union h2u { half2_t h; unsigned u; };

// ---- workspace layout (float-element offsets) ----
#define OFS_RELW   0                    // 200*128 padded relw
#define OFS_KVP    25600                // 50000 rows x 64 uints: k half + v half (256B/row)
#define OFS_Q      3225600              // 50000*128 padded q
#define OFS_BNPART 9625600              // 200 * AGG_NB
#define OFS_BNSC   10035200
#define OFS_BNSH   10035328
#define OFS_CNT    10035456
#define OFS_PART   10085632
#define OFS_BSUM   10135808
#define OFS_OFFS   10135872
#define OFS_RANK   10186048             // 800000 ints
#define OFS_PEDGE  10986048             // 800008 uints: src | ety<<17 (+8 pad)
#define OFS_WT     11786064             // 4*50*104 packed half2 W
#define WS_ELEMS   11806864

// fused prep: zero cnt + pedge pad (blocks 0..195), relw (196..295),
// wth pack (296..377)
__global__ __launch_bounds__(256) void prep_kernel(
    const float* __restrict__ wcomp, const float* __restrict__ ratt,
    const float* __restrict__ Wk, const float* __restrict__ Wq,
    const float* __restrict__ Wv, const float* __restrict__ Ws,
    float* __restrict__ relw, unsigned* __restrict__ Wth,
    int* __restrict__ cnt, unsigned* __restrict__ pedge)
{
    const int b = blockIdx.x;
    const int tid = threadIdx.x;
    if (b < 196) {
        int i = b * 256 + tid;
        if (i < 50176) cnt[i] = 0;
        if (b == 0 && tid < 8) pedge[N_EDGES + tid] = 0u;
    } else if (b < 296) {
        int o = (b - 196) * 256 + tid;
        if (o < 200 * 128) {
            int r = o / 128, c = o % 128;
            float acc = 0.f;
            if (c < 100) {
                #pragma unroll 10
                for (int k = 0; k < 50; ++k)
                    acc += wcomp[r * 50 + k] * ratt[k * 100 + c];
            }
            relw[o] = acc;
        }
    } else {
        int o = (b - 296) * 256 + tid;
        if (o < 4 * 50 * 104) {
            int m = o / 5200, rem = o % 5200, d2 = rem / 104, c = rem % 104;
            const float* W = (m == 0) ? Wk : (m == 1) ? Wq : (m == 2) ? Wv : Ws;
            float a = (c < 100) ? W[c * 100 + 2 * d2]     : 0.f;
            float bb = (c < 100) ? W[c * 100 + 2 * d2 + 1] : 0.f;
            h2u cv; cv.h = half2_t{(_Float16)a, (_Float16)bb};
            Wth[o] = cv.u;
        }
    }
}

// fused projections: proven fdot2 config (512 thr, 4x4 tile, 64-node tile,
// half2 LDS, XOR swizzle). k,v -> fp8 into ONE interleaved kvp row
// (k words 0-31, v words 32-63; 256B aligned; pads 0); q -> fp32 128-col
// rows (pad 0); s -> fp32 100-col rows.
__global__ __launch_bounds__(512) void proj_kernel(
    const float* __restrict__ X, const unsigned* __restrict__ Wth,
    const float* __restrict__ bk, const float* __restrict__ bq,
    const float* __restrict__ bv, const float* __restrict__ bs,
    unsigned* __restrict__ kvp, float* __restrict__ qo,
    float* __restrict__ so)
{
    __shared__ unsigned Xth[50][68];    // 13.6 KB
    __shared__ unsigned Wlh[50][104];   // 20.8 KB
    const int tid = threadIdx.x;
    const int nb  = blockIdx.x * 64;
    const int m   = blockIdx.y;

    const float* bp = (m == 0) ? bk : (m == 1) ? bq : (m == 2) ? bv : bs;

    for (int idx = tid; idx < 1300; idx += 512) {
        int r = idx / 26, c4 = idx % 26;
        uint4 w = ((const uint4*)(Wth + m * 5200 + r * 104))[c4];
        *(uint4*)&Wlh[r][c4 * 4] = w;
    }
    for (int idx = tid; idx < 1600; idx += 512) {
        int n = idx / 25, d4 = idx % 25;
        int node = nb + n;
        float4 x = (node < N_NODES)
                   ? ((const float4*)(X + (size_t)node * 100))[d4]
                   : make_float4(0.f, 0.f, 0.f, 0.f);
        const int col = n ^ ((d4 & 7) << 2);
        h2u c0, c1;
        c0.h = half2_t{(_Float16)x.x, (_Float16)x.y};
        c1.h = half2_t{(_Float16)x.z, (_Float16)x.w};
        Xth[2 * d4][col]     = c0.u;
        Xth[2 * d4 + 1][col] = c1.u;
    }
    __syncthreads();

    const int nt  = tid & 15;        // node group: nodes 4nt..4nt+3
    const int ct  = tid >> 4;        // col group 0..31 (25 active compute)
    const bool act = (ct < 25);
    const int cts  = act ? ct : 24;

    float acc[4][4];
    #pragma unroll
    for (int i = 0; i < 4; ++i)
        #pragma unroll
        for (int j = 0; j < 4; ++j) acc[i][j] = 0.f;

    #pragma unroll 5
    for (int d2 = 0; d2 < 50; ++d2) {
        const int key = ((d2 >> 1) & 7) << 2;
        const uint4 xv = *(const uint4*)&Xth[d2][(4 * nt) ^ key];
        const uint4 wv = *(const uint4*)&Wlh[d2][4 * cts];
        h2u x0, x1, x2, x3, w0, w1, w2, w3;
        x0.u = xv.x; x1.u = xv.y; x2.u = xv.z; x3.u = xv.w;
        w0.u = wv.x; w1.u = wv.y; w2.u = wv.z; w3.u = wv.w;
        acc[0][0] = FDOT2(x0.h, w0.h, acc[0][0]);
        acc[0][1] = FDOT2(x0.h, w1.h, acc[0][1]);
        acc[0][2] = FDOT2(x0.h, w2.h, acc[0][2]);
        acc[0][3] = FDOT2(x0.h, w3.h, acc[0][3]);
        acc[1][0] = FDOT2(x1.h, w0.h, acc[1][0]);
        acc[1][1] = FDOT2(x1.h, w1.h, acc[1][1]);
        acc[1][2] = FDOT2(x1.h, w2.h, acc[1][2]);
        acc[1][3] = FDOT2(x1.h, w3.h, acc[1][3]);
        acc[2][0] = FDOT2(x2.h, w0.h, acc[2][0]);
        acc[2][1] = FDOT2(x2.h, w1.h, acc[2][1]);
        acc[2][2] = FDOT2(x2.h, w2.h, acc[2][2]);
        acc[2][3] = FDOT2(x2.h, w3.h, acc[2][3]);
        acc[3][0] = FDOT2(x3.h, w0.h, acc[3][0]);
        acc[3][1] = FDOT2(x3.h, w1.h, acc[3][1]);
        acc[3][2] = FDOT2(x3.h, w2.h, acc[3][2]);
        acc[3][3] = FDOT2(x3.h, w3.h, acc[3][3]);
    }

    const float4 bb = act ? *(const float4*)(bp + ct * 4)
                          : make_float4(0.f, 0.f, 0.f, 0.f);
    if (m == 0 || m == 2) {
        const int wofs = (m == 0) ? ct : (32 + ct);
        #pragma unroll
        for (int i = 0; i < 4; ++i) {
            const int node = nb + nt * 4 + i;
            if (node < N_NODES) {
                unsigned wdo = 0u;
                if (act) {
                    int wd = 0;
                    wd = __builtin_amdgcn_cvt_pk_fp8_f32(
                        acc[i][0] + bb.x, acc[i][1] + bb.y, wd, false);
                    wd = __builtin_amdgcn_cvt_pk_fp8_f32(
                        acc[i][2] + bb.z, acc[i][3] + bb.w, wd, true);
                    wdo = (unsigned)wd;
                }
                kvp[(size_t)node * 64 + wofs] = wdo;
            }
        }
    } else if (m == 1) {
        #pragma unroll
        for (int i = 0; i < 4; ++i) {
            const int node = nb + nt * 4 + i;
            if (node < N_NODES) {
                float4 r = act ? make_float4(acc[i][0] + bb.x, acc[i][1] + bb.y,
                                             acc[i][2] + bb.z, acc[i][3] + bb.w)
                               : make_float4(0.f, 0.f, 0.f, 0.f);
                *(float4*)(qo + (size_t)node * 128 + ct * 4) = r;
            }
        }
    } else {
        if (act) {
            #pragma unroll
            for (int i = 0; i < 4; ++i) {
                const int node = nb + nt * 4 + i;
                if (node < N_NODES) {
                    float4 r = make_float4(acc[i][0] + bb.x, acc[i][1] + bb.y,
                                           acc[i][2] + bb.z, acc[i][3] + bb.w);
                    *(float4*)(so + (size_t)node * 100 + ct * 4) = r;
                }
            }
        }
    }
}

// histogram + per-edge rank (atomicAdd return value)
__global__ __launch_bounds__(256) void hist_kernel(
    const int* __restrict__ dst, int* __restrict__ cnt, int* __restrict__ rank)
{
    int e = blockIdx.x * 256 + threadIdx.x;
    if (e < N_EDGES) rank[e] = atomicAdd(&cnt[dst[e]], 1);
}

__global__ __launch_bounds__(1024) void scanA_kernel(
    const int* __restrict__ cnt, int* __restrict__ partial, int* __restrict__ bsum)
{
    __shared__ int buf[1024];
    int tid = threadIdx.x;
    int i = blockIdx.x * 1024 + tid;
    int val = (i < N_NODES) ? cnt[i] : 0;
    buf[tid] = val;
    __syncthreads();
    for (int off = 1; off < 1024; off <<= 1) {
        int t = (tid >= off) ? buf[tid - off] : 0;
        __syncthreads();
        buf[tid] += t;
        __syncthreads();
    }
    int incl = buf[tid];
    if (i < N_NODES) partial[i] = incl - val;
    if (tid == 1023) bsum[blockIdx.x] = incl;
}

__global__ __launch_bounds__(1024) void scanB_kernel(
    const int* __restrict__ partial, const int* __restrict__ bsum,
    int* __restrict__ offs)
{
    __shared__ int bs[64];
    int tid = threadIdx.x;
    if (tid < SCAN_NB) bs[tid] = bsum[tid];
    __syncthreads();
    if (tid == 0) {
        int run = 0;
        for (int b = 0; b < SCAN_NB; ++b) { int t = bs[b]; bs[b] = run; run += t; }
    }
    __syncthreads();
    for (int i = tid; i < N_NODES; i += 1024) offs[i] = partial[i] + bs[i >> 10];
    if (tid == 0) offs[N_NODES] = N_EDGES;
}

// scatter: NO atomics -- pos = offs[dst] + rank. ONE 4B word per edge.
__global__ __launch_bounds__(256) void scatter_kernel(
    const int* __restrict__ src, const int* __restrict__ dst,
    const int* __restrict__ ety, const int* __restrict__ offs,
    const int* __restrict__ rank, unsigned* __restrict__ pedge)
{
    int e = blockIdx.x * 256 + threadIdx.x;
    if (e >= N_EDGES) return;
    int d = dst[e];
    pedge[offs[d] + rank[e]] = (unsigned)src[e] | ((unsigned)ety[e] << 17);
}

// fused attention + aggregate: one wave per node; 8 edges per iteration
// (two per 16-lane group -> two independent dot/reduce chains). All lanes
// read the iteration's 8 pedge words directly (L1 broadcast) and issue all
// 8 v-gathers immediately, overlapping the dot+reduce. Only the weights
// cross lanes (8 shfl). Tail: pedge padded (8 zero words), weights masked.
__global__ __launch_bounds__(256) void agg_kernel(
    const int* __restrict__ offs, const unsigned* __restrict__ pedge,
    const unsigned* __restrict__ kvp, const float* __restrict__ q,
    const float* __restrict__ relw, const float* __restrict__ alpha,
    float* __restrict__ out, float* __restrict__ bnpart)
{
    __shared__ float ls[100], lq[100];
    const int tid = threadIdx.x;
    if (tid < 100) { ls[tid] = 0.f; lq[tid] = 0.f; }
    __syncthreads();
    const int lane = tid & 63;
    const int j    = lane & 15;       // quad index within group
    const int g16  = lane >> 4;       // edge group 0..3
    const int gwave = blockIdx.x * 4 + (tid >> 6);
    const int nwaves = AGG_NB * 4;
    const float a = 1.f / (1.f + __expf(-alpha[0]));
    const float b = 1.f - a;
    const bool act = (lane < 50);
    const unsigned short* kv16 = (const unsigned short*)kvp;
    float sx = 0.f, sy = 0.f, qx = 0.f, qy = 0.f;

    for (int n = gwave; n < N_NODES; n += nwaves) {
        const int beg = offs[n], end = offs[n + 1];
        const float4 qa = ((const float4*)(q + (size_t)n * 128))[j];
        const float4 qb = ((const float4*)(q + (size_t)n * 128))[j + 16];
        float ax = 0.f, ay = 0.f, wsum = 0.f;
        for (int i = beg; i < end; i += 8) {
            // v-gathers for all 8 edges (uniform pedge reads, issue early;
            // reads past `end` hit next node's edges or the zero pad --
            // their weights are masked to 0 below)
            floatx2 vv[8];
            #pragma unroll
            for (int m = 0; m < 8; ++m) {
                const int sm = (int)(pedge[i + m] & 0x1FFFFu);
                const unsigned short vh = kv16[(size_t)sm * 128 + 64 + lane];
                vv[m] = __builtin_amdgcn_cvt_pk_f32_fp8((int)vh, false);
            }
            // two own-edge dots per lane (edges i+g16 and i+g16+4)
            const unsigned pwA = pedge[i + g16];
            const unsigned pwB = pedge[i + g16 + 4];
            const int sA = (int)(pwA & 0x1FFFFu), tA = (int)(pwA >> 17);
            const int sB = (int)(pwB & 0x1FFFFu), tB = (int)(pwB >> 17);
            const unsigned* krA = kvp + (size_t)sA * 64;
            const unsigned* krB = kvp + (size_t)sB * 64;
            const unsigned kA0 = krA[j], kA1 = krA[j + 16];
            const unsigned kB0 = krB[j], kB1 = krB[j + 16];
            const float4 wA0 = ((const float4*)(relw + tA * 128))[j];
            const float4 wA1 = ((const float4*)(relw + tA * 128))[j + 16];
            const float4 wB0 = ((const float4*)(relw + tB * 128))[j];
            const float4 wB1 = ((const float4*)(relw + tB * 128))[j + 16];
            const floatx2 a0 = __builtin_amdgcn_cvt_pk_f32_fp8((int)kA0, false);
            const floatx2 a1 = __builtin_amdgcn_cvt_pk_f32_fp8((int)kA0, true);
            const floatx2 a2 = __builtin_amdgcn_cvt_pk_f32_fp8((int)kA1, false);
            const floatx2 a3 = __builtin_amdgcn_cvt_pk_f32_fp8((int)kA1, true);
            const floatx2 b0 = __builtin_amdgcn_cvt_pk_f32_fp8((int)kB0, false);
            const floatx2 b1 = __builtin_amdgcn_cvt_pk_f32_fp8((int)kB0, true);
            const floatx2 b2 = __builtin_amdgcn_cvt_pk_f32_fp8((int)kB1, false);
            const floatx2 b3 = __builtin_amdgcn_cvt_pk_f32_fp8((int)kB1, true);
            float pa = a0[0] * wA0.x * qa.x + a0[1] * wA0.y * qa.y
                     + a1[0] * wA0.z * qa.z + a1[1] * wA0.w * qa.w
                     + a2[0] * wA1.x * qb.x + a2[1] * wA1.y * qb.y
                     + a3[0] * wA1.z * qb.z + a3[1] * wA1.w * qb.w;
            float pb = b0[0] * wB0.x * qa.x + b0[1] * wB0.y * qa.y
                     + b1[0] * wB0.z * qa.z + b1[1] * wB0.w * qa.w
                     + b2[0] * wB1.x * qb.x + b2[1] * wB1.y * qb.y
                     + b3[0] * wB1.z * qb.z + b3[1] * wB1.w * qb.w;
            #pragma unroll
            for (int off = 1; off < 16; off <<= 1) {
                pa += __shfl_xor(pa, off, 16);
                pb += __shfl_xor(pb, off, 16);
            }
            const float wgtA = (i + g16 < end)     ? __expf(pa) : 0.f;
            const float wgtB = (i + g16 + 4 < end) ? __expf(pb) : 0.f;
            float w[8];
            w[0] = __shfl(wgtA, 0, 64);  w[1] = __shfl(wgtA, 16, 64);
            w[2] = __shfl(wgtA, 32, 64); w[3] = __shfl(wgtA, 48, 64);
            w[4] = __shfl(wgtB, 0, 64);  w[5] = __shfl(wgtB, 16, 64);
            w[6] = __shfl(wgtB, 32, 64); w[7] = __shfl(wgtB, 48, 64);
            #pragma unroll
            for (int m = 0; m < 8; ++m) {
                wsum += w[m];
                ax += w[m] * vv[m][0];
                ay += w[m] * vv[m][1];
            }
        }
        const float inv = (wsum > 0.f) ? 1.f / wsum : 0.f;
        if (act) {
            float2* po = (float2*)(out + (size_t)n * 100);
            float2 cur = po[lane];
            float v0 = a * cur.x + b * ax * inv;
            float v1 = a * cur.y + b * ay * inv;
            po[lane] = make_float2(v0, v1);
            sx += v0; qx += v0 * v0;
            sy += v1; qy += v1 * v1;
        }
    }
    if (act) {
        atomicAdd(&ls[2 * lane], sx);     atomicAdd(&ls[2 * lane + 1], sy);
        atomicAdd(&lq[2 * lane], qx);     atomicAdd(&lq[2 * lane + 1], qy);
    }
    __syncthreads();
    if (tid < 100) {
        bnpart[(size_t)tid * AGG_NB + blockIdx.x]         = ls[tid];
        bnpart[(size_t)(tid + 100) * AGG_NB + blockIdx.x] = lq[tid];
    }
}

__global__ __launch_bounds__(256) void bnfin_kernel(
    const float* __restrict__ bnpart,
    const float* __restrict__ gamma, const float* __restrict__ beta,
    float* __restrict__ bnsc, float* __restrict__ bnsh)
{
    const int c = blockIdx.x * 4 + (threadIdx.x >> 6);
    const int lane = threadIdx.x & 63;
    if (c >= 100) return;
    float s = 0.f, q = 0.f;
    for (int b2 = lane; b2 < AGG_NB; b2 += 64) {
        s += bnpart[(size_t)c * AGG_NB + b2];
        q += bnpart[(size_t)(c + 100) * AGG_NB + b2];
    }
    #pragma unroll
    for (int off = 32; off > 0; off >>= 1) {
        s += __shfl_xor(s, off, 64);
        q += __shfl_xor(q, off, 64);
    }
    if (lane == 0) {
        const float inv_n = 1.f / (float)N_NODES;
        float mean = s * inv_n;
        float var = q * inv_n - mean * mean;
        float sc = gamma[c] * rsqrtf(var + BN_EPS);
        bnsc[c] = sc;
        bnsh[c] = beta[c] - mean * sc;
    }
}

// fused: BN-apply+tanh (blocks < 2048) and r_out GEMM (blocks >= 2048)
__global__ __launch_bounds__(256) void applyrout_kernel(
    float* __restrict__ out, const float* __restrict__ bnsc,
    const float* __restrict__ bnsh,
    const float* __restrict__ rf, const float* __restrict__ Wr,
    const float* __restrict__ br)
{
    if (blockIdx.x < 2048) {
        const int total4 = N_NODES * 25;
        for (int idx = blockIdx.x * 256 + threadIdx.x; idx < total4; idx += 2048 * 256) {
            float4* p = ((float4*)out) + idx;
            const int c = (idx % 25) * 4;
            float4 t = *p;
            t.x = tanhf(t.x * bnsc[c]     + bnsh[c]);
            t.y = tanhf(t.y * bnsc[c + 1] + bnsh[c + 1]);
            t.z = tanhf(t.z * bnsc[c + 2] + bnsh[c + 2]);
            t.w = tanhf(t.w * bnsc[c + 3] + bnsh[c + 3]);
            *p = t;
        }
    } else {
        int o = (blockIdx.x - 2048) * 256 + threadIdx.x;
        if (o < 200 * 100) {
            int r = o / 100, c = o % 100;
            float acc = br[c];
            #pragma unroll 10
            for (int d = 0; d < 100; ++d) acc += rf[r * 100 + d] * Wr[c * 100 + d];
            out[N_NODES * 100 + o] = acc;
        }
    }
}

extern "C" void kernel_launch(void* const* d_in, const int* in_sizes, int n_in,
                              void* d_out, int out_size, void* d_ws, size_t ws_size,
                              hipStream_t stream) {
    const float* X     = (const float*)d_in[0];
    const float* rfeat = (const float*)d_in[1];
    const int*   src   = (const int*)d_in[2];
    const int*   dst   = (const int*)d_in[3];
    const int*   ety   = (const int*)d_in[4];
    const float* Wsw   = (const float*)d_in[6];
    const float* Wsb   = (const float*)d_in[7];
    const float* Wkw   = (const float*)d_in[8];
    const float* Wkb   = (const float*)d_in[9];
    const float* Wqw   = (const float*)d_in[10];
    const float* Wqb   = (const float*)d_in[11];
    const float* Wvw   = (const float*)d_in[12];
    const float* Wvb   = (const float*)d_in[13];
    const float* Wrw   = (const float*)d_in[14];
    const float* Wrb   = (const float*)d_in[15];
    const float* ratt  = (const float*)d_in[16];
    const float* wcomp = (const float*)d_in[17];
    const float* alpha = (const float*)d_in[18];
    const float* gamma = (const float*)d_in[20];
    const float* beta  = (const float*)d_in[21];

    float* out = (float*)d_out;
    float* ws  = (float*)d_ws;
    if (ws_size < (size_t)WS_ELEMS * sizeof(float)) return;

    float* relw          = ws + OFS_RELW;
    unsigned* kvp        = (unsigned*)(ws + OFS_KVP);
    float* q             = ws + OFS_Q;
    float* bnpart        = ws + OFS_BNPART;
    float* bnsc          = ws + OFS_BNSC;
    float* bnsh          = ws + OFS_BNSH;
    unsigned* Wth        = (unsigned*)(ws + OFS_WT);
    int* cnt             = (int*)(ws + OFS_CNT);
    int* partial         = (int*)(ws + OFS_PART);
    int* bsum            = (int*)(ws + OFS_BSUM);
    int* offs            = (int*)(ws + OFS_OFFS);
    int* rank            = (int*)(ws + OFS_RANK);
    unsigned* pedge      = (unsigned*)(ws + OFS_PEDGE);

    prep_kernel<<<196 + 100 + 82, 256, 0, stream>>>(
        wcomp, ratt, Wkw, Wqw, Wvw, Wsw, relw, Wth, cnt, pedge);
    proj_kernel<<<dim3((N_NODES + 63) / 64, 4), 512, 0, stream>>>(
        X, Wth, Wkb, Wqb, Wvb, Wsb, kvp, q, out);

    hist_kernel<<<(N_EDGES + 255) / 256, 256, 0, stream>>>(dst, cnt, rank);
    scanA_kernel<<<SCAN_NB, 1024, 0, stream>>>(cnt, partial, bsum);
    scanB_kernel<<<1, 1024, 0, stream>>>(partial, bsum, offs);
    scatter_kernel<<<(N_EDGES + 255) / 256, 256, 0, stream>>>(
        src, dst, ety, offs, rank, pedge);

    agg_kernel<<<AGG_NB, 256, 0, stream>>>(
        offs, pedge, kvp, q, relw, alpha, out, bnpart);
    bnfin_kernel<<<25, 256, 0, stream>>>(bnpart, gamma, beta, bnsc, bnsh);
    applyrout_kernel<<<2048 + (20000 + 255) / 256, 256, 0, stream>>>(
        out, bnsc, bnsh, rfeat, Wrw, Wrb);
}